// Round 4
// baseline (264.863 us; speedup 1.0000x reference)
//
#include <hip/hip_runtime.h>
#include <math.h>

#define D 256
#define SEGS 64
#define RPB 2048     // rows per block
#define THREADS 256  // 4 waves; each wave streams RPB/4 = 512 contiguous rows
#define RPW (RPB / 4)

typedef float f32x4 __attribute__((ext_vector_type(4)));

// ---- ordered-uint encoding for float atomicMax ----
// key(f) monotone in f; key >= 0x007FFFFF for all finite floats,
// so the zero-initialized key acts as a -inf identity.
__device__ __forceinline__ unsigned enc_f32(float f) {
  unsigned u = __float_as_uint(f);
  return (u & 0x80000000u) ? ~u : (u | 0x80000000u);
}
__device__ __forceinline__ float dec_f32(unsigned k) {
  unsigned u = (k & 0x80000000u) ? (k ^ 0x80000000u) : ~k;
  return __uint_as_float(u);
}

// init: zero sums/maxk and scan segment boundaries in one parallel pass.
// bounds[s] = lower_bound(idx, s) for s in [0, SEGS]; for each i in [0, n],
// with prev = idx[i-1] (or -1) and curv = idx[i] (or SEGS at i==n), every
// s in (prev, curv] gets bounds[s] = i. Sorted input => non-conflicting writes.
// idx width (int32 vs int64 little-endian) detected from the last int32 word:
// sorted data ends in 63 (int32) or the 0 high-word of an int64.
__global__ void init_kernel(const int* __restrict__ idx, int n,
                            float* __restrict__ sums,
                            unsigned* __restrict__ maxk,
                            int* __restrict__ bounds) {
  const int gid = blockIdx.x * blockDim.x + threadIdx.x;
  if (gid < SEGS * D) { sums[gid] = 0.0f; maxk[gid] = 0u; }
  const int stride = (idx[(size_t)n - 1] == 0) ? 2 : 1;
  const int gsz = gridDim.x * blockDim.x;
  for (int i = gid; i <= n; i += gsz) {
    const int prev = (i == 0) ? -1 : idx[(size_t)(i - 1) * stride];
    const int curv = (i == n) ? SEGS : idx[(size_t)i * stride];
    for (int s = prev + 1; s <= curv; ++s) bounds[s] = i;
  }
}

__global__ __launch_bounds__(THREADS, 2)
void agg_kernel(const float* __restrict__ feat, const int* __restrict__ bounds,
                float* __restrict__ sums, unsigned* __restrict__ maxk, int n) {
  __shared__ f32x4 lds_s[4][64];  // 4 KiB: per-wave partial sums
  __shared__ f32x4 lds_m[4][64];  // 4 KiB: per-wave partial maxes

  const int lane = threadIdx.x & 63;
  const int wave = threadIdx.x >> 6;
  const int r0 = blockIdx.x * RPB;
  const int rows = min(RPB, n - r0);

  // b_end = bounds[lane+1] = end row of segment `lane` (one coalesced load).
  const int b_end = bounds[lane + 1];
  // segment of row r = #{s : b_end[s] <= r} (correct across empty segments).
  const int segF = (int)__popcll(__ballot(b_end <= r0));
  const int segL = (int)__popcll(__ballot(b_end <= r0 + rows - 1));

  int i = r0 + wave * RPW;
  const int re = min(i + RPW, n);
  const float* base = feat + lane * 4;

  if (segF == segL) {
    // ---- fast path (block-uniform): whole block inside segment segF ----
    f32x4 sum = {0.f, 0.f, 0.f, 0.f};
    f32x4 mx  = {-INFINITY, -INFINITY, -INFINITY, -INFINITY};
#pragma unroll 8
    for (int k = i; k < re; ++k) {
      const f32x4 v = __builtin_nontemporal_load(
          reinterpret_cast<const f32x4*>(base + (size_t)k * D));
      sum += v;
      mx.x = __builtin_fmaxf(mx.x, v.x);
      mx.y = __builtin_fmaxf(mx.y, v.y);
      mx.z = __builtin_fmaxf(mx.z, v.z);
      mx.w = __builtin_fmaxf(mx.w, v.w);
    }
    lds_s[wave][lane] = sum;
    lds_m[wave][lane] = mx;
    __syncthreads();
    // combine across the 4 waves: thread t owns output column t.
    const int c = threadIdx.x;
    float s = 0.0f, m = -INFINITY;
#pragma unroll
    for (int w = 0; w < 4; ++w) {
      s += ((const float*)&lds_s[w][c >> 2])[c & 3];
      m = __builtin_fmaxf(m, ((const float*)&lds_m[w][c >> 2])[c & 3]);
    }
    atomicAdd(&sums[segF * D + c], s);
    atomicMax(&maxk[segF * D + c], enc_f32(m));
    return;
  }

  // ---- slow path: block straddles a boundary (<=63 blocks grid-wide) ----
  if (i >= re) return;
  int cur = (int)__popcll(__ballot(b_end <= i));
  while (true) {
    const int e = __shfl(b_end, cur);  // end of current segment
    const int j = min(re, e);          // invariant: j > i

    f32x4 sum = {0.f, 0.f, 0.f, 0.f};
    f32x4 mx  = {-INFINITY, -INFINITY, -INFINITY, -INFINITY};
#pragma unroll 8
    for (int k = i; k < j; ++k) {
      const f32x4 v = __builtin_nontemporal_load(
          reinterpret_cast<const f32x4*>(base + (size_t)k * D));
      sum += v;
      mx.x = __builtin_fmaxf(mx.x, v.x);
      mx.y = __builtin_fmaxf(mx.y, v.y);
      mx.z = __builtin_fmaxf(mx.z, v.z);
      mx.w = __builtin_fmaxf(mx.w, v.w);
    }

    float* sp = sums + cur * D + lane * 4;
    atomicAdd(sp + 0, sum.x); atomicAdd(sp + 1, sum.y);
    atomicAdd(sp + 2, sum.z); atomicAdd(sp + 3, sum.w);
    unsigned* mp = maxk + cur * D + lane * 4;
    atomicMax(mp + 0, enc_f32(mx.x)); atomicMax(mp + 1, enc_f32(mx.y));
    atomicMax(mp + 2, enc_f32(mx.z)); atomicMax(mp + 3, enc_f32(mx.w));

    if (j >= re) break;
    i = j;
    do { ++cur; } while (__shfl(b_end, cur) <= i);  // skip empty segments
  }
}

__global__ void finalize_kernel(const float* __restrict__ sums,
                                const unsigned* __restrict__ maxk,
                                const int* __restrict__ bounds,
                                float* __restrict__ out) {
  int t = blockIdx.x * blockDim.x + threadIdx.x;
  if (t >= SEGS * 2 * D) return;
  int s = t / (2 * D);
  int j = t % (2 * D);
  int c = bounds[s + 1] - bounds[s];
  float v;
  if (j < D)
    v = (c > 0) ? sums[s * D + j] / (float)c : 0.0f;
  else
    v = (c > 0) ? dec_f32(maxk[s * D + (j - D)]) : 0.0f;
  out[t] = v;
}

extern "C" void kernel_launch(void* const* d_in, const int* in_sizes, int n_in,
                              void* d_out, int out_size, void* d_ws, size_t ws_size,
                              hipStream_t stream) {
  const float* feat = (const float*)d_in[0];
  const int*   idx  = (const int*)d_in[1];
  const int n = in_sizes[1];
  float* out = (float*)d_out;

  char* ws = (char*)d_ws;
  float*    sums   = (float*)ws;                       // 64 KiB
  unsigned* maxk   = (unsigned*)(ws + SEGS * D * 4);   // 64 KiB
  int*      bounds = (int*)(ws + 2 * SEGS * D * 4);    // 65 ints

  init_kernel<<<1024, THREADS, 0, stream>>>(idx, n, sums, maxk, bounds);

  const int nblocks = (n + RPB - 1) / RPB;
  agg_kernel<<<nblocks, THREADS, 0, stream>>>(feat, bounds, sums, maxk, n);

  finalize_kernel<<<(SEGS * 2 * D + THREADS - 1) / THREADS, THREADS, 0, stream>>>(
      sums, maxk, bounds, out);
}

// Round 5
// 231.644 us; speedup vs baseline: 1.1434x; 1.1434x over previous
//
#include <hip/hip_runtime.h>
#include <math.h>

#define D 256
#define SEGS 64
#define RPB 512      // rows per block
#define THREADS 256  // 4 waves; each wave streams RPB/4 = 128 contiguous rows

typedef float f32x4 __attribute__((ext_vector_type(4)));

// ---- ordered-uint encoding for float atomicMax ----
// key(f) monotone in f; key >= 0x007FFFFF for all finite floats,
// so the zero-initialized key acts as a -inf identity.
__device__ __forceinline__ unsigned enc_f32(float f) {
  unsigned u = __float_as_uint(f);
  return (u & 0x80000000u) ? ~u : (u | 0x80000000u);
}
__device__ __forceinline__ float dec_f32(unsigned k) {
  unsigned u = (k & 0x80000000u) ? (k ^ 0x80000000u) : ~k;
  return __uint_as_float(u);
}

// init: block s zeros segment s's ws slice and binary-searches bounds[s+1] =
// lower_bound(idx, s+1). idx width (int32 vs int64) detected from the last
// int32 word: sorted data ends in 63 (int32) or the 0 high-word (int64).
__global__ void init_kernel(const int* __restrict__ idx, int n,
                            float* __restrict__ sums,
                            unsigned* __restrict__ maxk,
                            int* __restrict__ bounds) {
  const int s = blockIdx.x;
  if (threadIdx.x < D) {
    sums[s * D + threadIdx.x] = 0.0f;
    maxk[s * D + threadIdx.x] = 0u;
  }
  if (threadIdx.x == 0) {
    const int stride = (idx[(size_t)n - 1] == 0) ? 2 : 1;
    const int v = s + 1;
    int lo = 0, hi = n;
    while (lo < hi) {
      int mid = (lo + hi) >> 1;
      if (idx[(size_t)mid * stride] < v) lo = mid + 1; else hi = mid;
    }
    bounds[s + 1] = lo;
    if (s == 0) bounds[0] = 0;
  }
}

__global__ __launch_bounds__(THREADS, 4)
void agg_kernel(const float* __restrict__ feat, const int* __restrict__ bounds,
                float* __restrict__ sums, unsigned* __restrict__ maxk, int n) {
  const int lane = threadIdx.x & 63;
  const int wave = threadIdx.x >> 6;
  int i = blockIdx.x * RPB + wave * (RPB / 4);
  const int re = min(i + (RPB / 4), n);
  if (i >= re) return;

  // b_end = bounds[lane+1] = end row of segment `lane` (one coalesced load).
  const int b_end = bounds[lane + 1];
  // segment of row i: number of segment-ends <= i (handles empties).
  int cur = (int)__popcll(__ballot(b_end <= i));

  const float* base = feat + lane * 4;

  while (true) {
    const int e = __shfl(b_end, cur);   // end of current segment
    const int j = min(re, e);           // invariant: j > i

    f32x4 sum = {0.f, 0.f, 0.f, 0.f};
    f32x4 mx  = {-INFINITY, -INFINITY, -INFINITY, -INFINITY};
#pragma unroll 8
    for (int k = i; k < j; ++k) {
      const f32x4 v = *reinterpret_cast<const f32x4*>(base + (size_t)k * D);
      sum += v;
      mx.x = __builtin_fmaxf(mx.x, v.x);
      mx.y = __builtin_fmaxf(mx.y, v.y);
      mx.z = __builtin_fmaxf(mx.z, v.z);
      mx.w = __builtin_fmaxf(mx.w, v.w);
    }

    float* sp = sums + cur * D + lane * 4;
    atomicAdd(sp + 0, sum.x); atomicAdd(sp + 1, sum.y);
    atomicAdd(sp + 2, sum.z); atomicAdd(sp + 3, sum.w);
    unsigned* mp = maxk + cur * D + lane * 4;
    atomicMax(mp + 0, enc_f32(mx.x)); atomicMax(mp + 1, enc_f32(mx.y));
    atomicMax(mp + 2, enc_f32(mx.z)); atomicMax(mp + 3, enc_f32(mx.w));

    if (j >= re) break;
    i = j;
    do { ++cur; } while (__shfl(b_end, cur) <= i);  // skip empty segments
  }
}

__global__ void finalize_kernel(const float* __restrict__ sums,
                                const unsigned* __restrict__ maxk,
                                const int* __restrict__ bounds,
                                float* __restrict__ out) {
  int t = blockIdx.x * blockDim.x + threadIdx.x;
  if (t >= SEGS * 2 * D) return;
  int s = t / (2 * D);
  int j = t % (2 * D);
  int c = bounds[s + 1] - bounds[s];
  float v;
  if (j < D)
    v = (c > 0) ? sums[s * D + j] / (float)c : 0.0f;
  else
    v = (c > 0) ? dec_f32(maxk[s * D + (j - D)]) : 0.0f;
  out[t] = v;
}

extern "C" void kernel_launch(void* const* d_in, const int* in_sizes, int n_in,
                              void* d_out, int out_size, void* d_ws, size_t ws_size,
                              hipStream_t stream) {
  const float* feat = (const float*)d_in[0];
  const int*   idx  = (const int*)d_in[1];
  const int n = in_sizes[1];
  float* out = (float*)d_out;

  char* ws = (char*)d_ws;
  float*    sums   = (float*)ws;                       // 64 KiB
  unsigned* maxk   = (unsigned*)(ws + SEGS * D * 4);   // 64 KiB
  int*      bounds = (int*)(ws + 2 * SEGS * D * 4);    // 65 ints

  init_kernel<<<SEGS, THREADS, 0, stream>>>(idx, n, sums, maxk, bounds);

  const int nblocks = (n + RPB - 1) / RPB;
  agg_kernel<<<nblocks, THREADS, 0, stream>>>(feat, bounds, sums, maxk, n);

  finalize_kernel<<<(SEGS * 2 * D + THREADS - 1) / THREADS, THREADS, 0, stream>>>(
      sums, maxk, bounds, out);
}

// Round 6
// 221.952 us; speedup vs baseline: 1.1933x; 1.0437x over previous
//
#include <hip/hip_runtime.h>
#include <math.h>

#define D 256
#define SEGS 64
#define RPB 512      // rows per block
#define THREADS 256  // 4 waves; each wave streams RPB/4 = 128 contiguous rows

typedef float f32x4 __attribute__((ext_vector_type(4)));

// ---- ordered-uint encoding for float atomicMax ----
__device__ __forceinline__ unsigned enc_f32(float f) {
  unsigned u = __float_as_uint(f);
  return (u & 0x80000000u) ? ~u : (u | 0x80000000u);
}
__device__ __forceinline__ float dec_f32(unsigned k) {
  unsigned u = (k & 0x80000000u) ? (k ^ 0x80000000u) : ~k;
  return __uint_as_float(u);
}

// init: block s zeros segment s's ws slice and binary-searches bounds[s+1] =
// lower_bound(idx, s+1). idx width (int32 vs int64) detected from the last
// int32 word: sorted data ends in 63 (int32) or the 0 high-word (int64).
__global__ void init_kernel(const int* __restrict__ idx, int n,
                            float* __restrict__ sums,
                            unsigned* __restrict__ maxk,
                            int* __restrict__ bounds) {
  const int s = blockIdx.x;
  if (threadIdx.x < D) {
    sums[s * D + threadIdx.x] = 0.0f;
    maxk[s * D + threadIdx.x] = 0u;
  }
  if (threadIdx.x == 0) {
    const int stride = (idx[(size_t)n - 1] == 0) ? 2 : 1;
    const int v = s + 1;
    int lo = 0, hi = n;
    while (lo < hi) {
      int mid = (lo + hi) >> 1;
      if (idx[(size_t)mid * stride] < v) lo = mid + 1; else hi = mid;
    }
    bounds[s + 1] = lo;
    if (s == 0) bounds[0] = 0;
  }
}

__device__ __forceinline__ void load8(const float* __restrict__ base, int k,
                                      f32x4* b) {
#pragma unroll
  for (int t = 0; t < 8; ++t)
    b[t] = __builtin_nontemporal_load(
        reinterpret_cast<const f32x4*>(base + (size_t)(k + t) * D));
}

__device__ __forceinline__ void acc8(const f32x4* b, f32x4& sum, f32x4& mx) {
#pragma unroll
  for (int t = 0; t < 8; ++t) {
    sum += b[t];
    mx.x = __builtin_fmaxf(mx.x, b[t].x);
    mx.y = __builtin_fmaxf(mx.y, b[t].y);
    mx.z = __builtin_fmaxf(mx.z, b[t].z);
    mx.w = __builtin_fmaxf(mx.w, b[t].w);
  }
}

__global__ __launch_bounds__(THREADS, 4)
void agg_kernel(const float* __restrict__ feat, const int* __restrict__ bounds,
                float* __restrict__ sums, unsigned* __restrict__ maxk, int n) {
  const int lane = threadIdx.x & 63;
  const int wave = threadIdx.x >> 6;
  int i = blockIdx.x * RPB + wave * (RPB / 4);
  const int re = min(i + (RPB / 4), n);
  if (i >= re) return;

  // b_end = bounds[lane+1] = end row of segment `lane` (one coalesced load).
  const int b_end = bounds[lane + 1];
  int cur = (int)__popcll(__ballot(b_end <= i));  // segment of row i

  const float* base = feat + lane * 4;

  while (true) {
    const int e = __shfl(b_end, cur);   // end of current segment
    const int j = min(re, e);           // invariant: j > i

    f32x4 sum = {0.f, 0.f, 0.f, 0.f};
    f32x4 mx  = {-INFINITY, -INFINITY, -INFINITY, -INFINITY};

    int k = i;
    if (j - k >= 32) {
      // software-pipelined double-buffer: 8-16 loads (8-16 KB) in flight
      f32x4 A[8], B[8];
      load8(base, k, A);
      load8(base, k + 8, B);
      k += 16;
      for (; k + 16 <= j; k += 16) {
        acc8(A, sum, mx);
        load8(base, k, A);
        acc8(B, sum, mx);
        load8(base, k + 8, B);
      }
      acc8(A, sum, mx);
      acc8(B, sum, mx);
    }
#pragma unroll 4
    for (; k < j; ++k) {
      const f32x4 v = __builtin_nontemporal_load(
          reinterpret_cast<const f32x4*>(base + (size_t)k * D));
      sum += v;
      mx.x = __builtin_fmaxf(mx.x, v.x);
      mx.y = __builtin_fmaxf(mx.y, v.y);
      mx.z = __builtin_fmaxf(mx.z, v.z);
      mx.w = __builtin_fmaxf(mx.w, v.w);
    }

    float* sp = sums + cur * D + lane * 4;
    atomicAdd(sp + 0, sum.x); atomicAdd(sp + 1, sum.y);
    atomicAdd(sp + 2, sum.z); atomicAdd(sp + 3, sum.w);
    unsigned* mp = maxk + cur * D + lane * 4;
    atomicMax(mp + 0, enc_f32(mx.x)); atomicMax(mp + 1, enc_f32(mx.y));
    atomicMax(mp + 2, enc_f32(mx.z)); atomicMax(mp + 3, enc_f32(mx.w));

    if (j >= re) break;
    i = j;
    do { ++cur; } while (__shfl(b_end, cur) <= i);  // skip empty segments
  }
}

__global__ void finalize_kernel(const float* __restrict__ sums,
                                const unsigned* __restrict__ maxk,
                                const int* __restrict__ bounds,
                                float* __restrict__ out) {
  int t = blockIdx.x * blockDim.x + threadIdx.x;
  if (t >= SEGS * 2 * D) return;
  int s = t / (2 * D);
  int j = t % (2 * D);
  int c = bounds[s + 1] - bounds[s];
  float v;
  if (j < D)
    v = (c > 0) ? sums[s * D + j] / (float)c : 0.0f;
  else
    v = (c > 0) ? dec_f32(maxk[s * D + (j - D)]) : 0.0f;
  out[t] = v;
}

extern "C" void kernel_launch(void* const* d_in, const int* in_sizes, int n_in,
                              void* d_out, int out_size, void* d_ws, size_t ws_size,
                              hipStream_t stream) {
  const float* feat = (const float*)d_in[0];
  const int*   idx  = (const int*)d_in[1];
  const int n = in_sizes[1];
  float* out = (float*)d_out;

  char* ws = (char*)d_ws;
  float*    sums   = (float*)ws;                       // 64 KiB
  unsigned* maxk   = (unsigned*)(ws + SEGS * D * 4);   // 64 KiB
  int*      bounds = (int*)(ws + 2 * SEGS * D * 4);    // 65 ints

  init_kernel<<<SEGS, THREADS, 0, stream>>>(idx, n, sums, maxk, bounds);

  const int nblocks = (n + RPB - 1) / RPB;
  agg_kernel<<<nblocks, THREADS, 0, stream>>>(feat, bounds, sums, maxk, n);

  finalize_kernel<<<(SEGS * 2 * D + THREADS - 1) / THREADS, THREADS, 0, stream>>>(
      sums, maxk, bounds, out);
}